// Round 7
// baseline (562.951 us; speedup 1.0000x reference)
//
#include <hip/hip_runtime.h>

// RegimeAwareStudent: B=524288 tokens, ALL tensors fp32 (per reference), rid int32.
//   h  = relu(x @ fe_w1 + fe_b1)           [B,128]->[B,256]
//   f  = relu(h @ fe_w2 + fe_b2)           [B,256]->[B,128]
//   c  = concat(f, emb[rid])               [B,192]
//   eh = relu(c @ ew1[rid] + eb1[rid])     [B,192]->[B,256]
//   o  = eh @ ew2[rid] + eb2[rid]          [B,256]->[B,1]
// bf16 MFMA path (RNE at staging), fp32 accumulate, fp32 out.
// R7 = R6's transposed GEMMs (operand swap; numerics verified by R6 pass)
// + BIAS FOLDED INTO ACC INIT (acc = bias; acc += W^T X^T), which hoists all
// bias/eb1 global loads out of the loops (R6's in-loop f32x4 loads are the
// prime suspect for its mystery 137MB HBM write traffic) and deletes the
// epilogue bias adds. Transposed D-layout keeps: b64 LDS epilogue stores,
// 4 bpermutes (not 16), stage-3 reduce = 2 shfls (not 16).
// Kept from R5: separate X/H regions, 4 barriers, emb-as-uniform-frag,
// 49.25KB LDS -> 3 blocks/CU, launch_bounds(256,3).

typedef short short8 __attribute__((ext_vector_type(8)));
typedef float f32x4  __attribute__((ext_vector_type(4)));
typedef unsigned int uint2v __attribute__((ext_vector_type(2)));

#define MFMA16 __builtin_amdgcn_mfma_f32_16x16x32_bf16

constexpr int B_TOK  = 524288;
constexpr int TM     = 64;                 // tokens per tile
constexpr int NTILES = B_TOK / TM;         // 8192, exact

// packed-weight layout in d_ws (ushort element offsets)
constexpr size_t PW1_OFF   = 0;            // fe_w1: 4kt*16nt*64lane*8 = 32768 el
constexpr size_t PW2_OFF   = 32768;        // fe_w2: 8kt*8nt*64*8      = 32768 el
constexpr size_t PE1_OFF   = 65536;        // ew1:   3 * 6kt*16nt*64*8 = 147456 el
constexpr size_t PE1_PER_R = 49152;
// total ws = 212992 ushort = 425,984 bytes

static __device__ __forceinline__ ushort f2bf(float f) {  // RNE (repack only)
    union { float f; unsigned int i; } x; x.f = f;
    unsigned int i = x.i;
    i += 0x7fffu + ((i >> 16) & 1u);
    return (ushort)(i >> 16);
}

// HW packed f32->bf16 (RNE): D[15:0]=bf16(lo), D[31:16]=bf16(hi)
static __device__ __forceinline__ unsigned pk_bf16(float lo, float hi) {
    unsigned r;
    asm("v_cvt_pk_bf16_f32 %0, %1, %2" : "=v"(r) : "v"(lo), "v"(hi));
    return r;
}

static __device__ __forceinline__ short8 pack8(f32x4 f0, f32x4 f1) {
    union { unsigned u[4]; short8 s; } r;
    r.u[0] = pk_bf16(f0[0], f0[1]);
    r.u[1] = pk_bf16(f0[2], f0[3]);
    r.u[2] = pk_bf16(f1[0], f1[1]);
    r.u[3] = pk_bf16(f1[2], f1[3]);
    return r.s;
}

// X/F tile [64][128] bf16, row stride 256B. XOR row&15 into byte bits 4-7.
static __device__ __forceinline__ int swzX(int row, int inb) {
    return row * 256 + (inb ^ ((row & 15) << 4));
}
// H tile [64][256] bf16, row stride 512B. XOR row&7 into byte bits 4-6.
static __device__ __forceinline__ int swzH(int row, int inb) {
    return row * 512 + (inb ^ ((row & 7) << 4));
}

// ---- weight repack: fp32 -> bf16 MFMA fragment layout ---------------------
// pw[frag=kt*NT+nt][lane][j] = bf16(W[kt*32 + (lane>>4)*8 + j][nt*16 + (lane&15)])
// (B-frag of W == A-frag of W^T; used as A in the transposed GEMMs.)
__global__ void repack_weights(const float* __restrict__ w1,
                               const float* __restrict__ w2,
                               const float* __restrict__ e1,
                               ushort* __restrict__ pw) {
    int t = blockIdx.x * 256 + threadIdx.x;       // 26624 threads total
    const float* src; int N, kt, nt; size_t dst;
    int lane = t & 63;
    if (t < 4096) {                                // fe_w1: K=128,N=256
        int frag = t >> 6; kt = frag >> 4; nt = frag & 15;
        src = w1; N = 256; dst = PW1_OFF + (size_t)t * 8;
    } else if (t < 8192) {                         // fe_w2: K=256,N=128
        int u = t - 4096; int frag = u >> 6; kt = frag >> 3; nt = frag & 7;
        src = w2; N = 128; dst = PW2_OFF + (size_t)u * 8;
    } else {                                       // ew1[r]: K=192,N=256
        int u = t - 8192; int reg = u / 6144; int v = u % 6144;
        int frag = v >> 6; kt = frag >> 4; nt = frag & 15;
        src = e1 + (size_t)reg * (192 * 256); N = 256;
        dst = PE1_OFF + (size_t)reg * PE1_PER_R + (size_t)v * 8;
    }
    int quad = lane >> 4, cc = lane & 15;
    int k0 = kt * 32 + quad * 8;
    int n  = nt * 16 + cc;
    short8 vv;
    #pragma unroll
    for (int j = 0; j < 8; ++j) vv[j] = (short)f2bf(src[(size_t)(k0 + j) * N + n]);
    *(short8*)(pw + dst) = vv;
}

// ---- fused main: 64 tokens per block, 256 threads = 4 waves ---------------
__global__ __launch_bounds__(256, 3) void fused_main(
    const float* __restrict__ x,
    const int*   __restrict__ rid,
    const ushort* __restrict__ pw,
    const float* __restrict__ fe_b1,
    const float* __restrict__ fe_b2,
    const float* __restrict__ emb,
    const float* __restrict__ eb1,
    const float* __restrict__ ew2,
    const float* __restrict__ eb2,
    float*       __restrict__ out) {
    __shared__ ushort sX[64 * 128];    // 16 KB: X tile, then F tile (slot rows)
    __shared__ ushort sH[64 * 256];    // 32 KB: H tile
    __shared__ float  sRed[64][4];     // 1 KB: per-wave partials

    const int t    = threadIdx.x;
    const int w    = t >> 6;
    const int lane = t & 63;
    const int quad = lane >> 4;
    const int cc   = lane & 15;
    const int ts   = blockIdx.x * TM;

    // ---- stage X into LDS, UNSORTED (token rows), swizzled ----
    #pragma unroll
    for (int it = 0; it < 4; ++it) {
        int chunk = it * 256 + t;
        int row = chunk >> 4, seg = chunk & 15;   // 8 floats per chunk
        const float* xr = x + (size_t)(ts + row) * 128 + seg * 8;
        f32x4 f0 = *(const f32x4*)xr;
        f32x4 f1 = *(const f32x4*)(xr + 4);
        *(short8*)((char*)sX + swzX(row, seg * 16)) = pack8(f0, f1);
    }

    // ---- per-wave (redundant, uniform) counting sort of the 64 tokens ----
    int slot, b1, b2, tos;
    {
        int myr = rid[ts + lane];
        unsigned long long below = (1ull << lane) - 1ull;
        int base = 0, bb1 = 0, bb2 = 0;
        slot = 0;
        #pragma unroll
        for (int r = 0; r < 3; ++r) {
            unsigned long long mask = __ballot(myr == r);
            if (myr == r) slot = base + __popcll(mask & below);
            base += __popcll(mask);
            if (r == 0) bb1 = base;
            if (r == 1) bb2 = base;
        }
        b1 = __builtin_amdgcn_readfirstlane(bb1);
        b2 = __builtin_amdgcn_readfirstlane(bb2);
        tos = __builtin_amdgcn_ds_permute(slot << 2, lane);  // slot s -> token
    }
    __syncthreads();   // (1) X visible

    // ---- stage 1: H^T = W1^T·X^T + b1 (folded); wave feats [w*64,w*64+64) --
    // acc init = bias (hoisted f32x4 loads, latency hidden under LDS reads).
    {
        f32x4 binit[4];
        #pragma unroll
        for (int nn = 0; nn < 4; ++nn)
            binit[nn] = *(const f32x4*)(fe_b1 + w * 64 + nn * 16 + quad * 4);
        f32x4 acc[4][4];
        #pragma unroll
        for (int m = 0; m < 4; ++m)
            #pragma unroll
            for (int nn = 0; nn < 4; ++nn) acc[m][nn] = binit[nn];
        #pragma unroll
        for (int kt = 0; kt < 4; ++kt) {
            short8 xb[4], wa[4];
            #pragma unroll
            for (int m = 0; m < 4; ++m)
                xb[m] = *(const short8*)((const char*)sX +
                        swzX(m * 16 + cc, kt * 64 + quad * 16));
            #pragma unroll
            for (int nn = 0; nn < 4; ++nn)
                wa[nn] = *(const short8*)(pw + PW1_OFF +
                        ((size_t)((kt * 16 + (w * 4 + nn)) * 64 + lane)) * 8);
            #pragma unroll
            for (int m = 0; m < 4; ++m)
                #pragma unroll
                for (int nn = 0; nn < 4; ++nn)
                    acc[m][nn] = MFMA16(wa[nn], xb[m], acc[m][nn], 0, 0, 0);
        }
        #pragma unroll
        for (int nn = 0; nn < 4; ++nn) {
            int fb = w * 64 + nn * 16 + quad * 4;
            #pragma unroll
            for (int m = 0; m < 4; ++m) {
                int token = m * 16 + cc;
                float v0 = fmaxf(acc[m][nn][0], 0.0f);
                float v1 = fmaxf(acc[m][nn][1], 0.0f);
                float v2 = fmaxf(acc[m][nn][2], 0.0f);
                float v3 = fmaxf(acc[m][nn][3], 0.0f);
                uint2v p; p[0] = pk_bf16(v0, v1); p[1] = pk_bf16(v2, v3);
                *(uint2v*)((char*)sH + swzH(token, fb * 2)) = p;
            }
        }
    }
    __syncthreads();   // (2) H visible; X region dead

    // ---- stage 2: F^T = W2^T·H^T + b2 (folded); wave feats [w*32,w*32+32) --
    {
        f32x4 binit[2];
        #pragma unroll
        for (int nn = 0; nn < 2; ++nn)
            binit[nn] = *(const f32x4*)(fe_b2 + w * 32 + nn * 16 + quad * 4);
        f32x4 acc[4][2];
        #pragma unroll
        for (int m = 0; m < 4; ++m)
            #pragma unroll
            for (int nn = 0; nn < 2; ++nn) acc[m][nn] = binit[nn];
        #pragma unroll
        for (int kt = 0; kt < 8; ++kt) {
            short8 hb[4], wa[2];
            #pragma unroll
            for (int m = 0; m < 4; ++m)
                hb[m] = *(const short8*)((const char*)sH +
                        swzH(m * 16 + cc, kt * 64 + quad * 16));
            #pragma unroll
            for (int nn = 0; nn < 2; ++nn)
                wa[nn] = *(const short8*)(pw + PW2_OFF +
                        ((size_t)((kt * 8 + (w * 2 + nn)) * 64 + lane)) * 8);
            #pragma unroll
            for (int m = 0; m < 4; ++m)
                #pragma unroll
                for (int nn = 0; nn < 2; ++nn)
                    acc[m][nn] = MFMA16(wa[nn], hb[m], acc[m][nn], 0, 0, 0);
        }
        // F written slot-scattered into sX region (1 bpermute + 2 b64 per m)
        #pragma unroll
        for (int m = 0; m < 4; ++m) {
            int token = m * 16 + cc;
            int sr = __builtin_amdgcn_ds_bpermute(token << 2, slot);
            #pragma unroll
            for (int nn = 0; nn < 2; ++nn) {
                int fb = w * 32 + nn * 16 + quad * 4;
                float v0 = fmaxf(acc[m][nn][0], 0.0f);
                float v1 = fmaxf(acc[m][nn][1], 0.0f);
                float v2 = fmaxf(acc[m][nn][2], 0.0f);
                float v3 = fmaxf(acc[m][nn][3], 0.0f);
                uint2v p; p[0] = pk_bf16(v0, v1); p[1] = pk_bf16(v2, v3);
                *(uint2v*)((char*)sX + swzX(sr, fb * 2)) = p;
            }
        }
    }
    __syncthreads();   // (3) F visible (slot space); H dead

    // ---- stage 3: per regime; wave feats [w*64,w*64+64) -------------------
    // D = ew1^T·C^T + eb1 (folded). Lane ends with 16 feature-partials of ONE
    // token; dot with ew2 in-lane, then 2 shfls across quads.
    for (int r = 0; r < 3; ++r) {
        int lo = (r == 0) ? 0  : (r == 1 ? b1 : b2);
        int hi = (r == 0) ? b1 : (r == 1 ? b2 : 64);
        if (lo >= hi) continue;               // block-uniform
        const ushort* pe = pw + PE1_OFF + (size_t)r * PE1_PER_R;
        short8 bEmb[2];
        #pragma unroll
        for (int e = 0; e < 2; ++e) {
            const float* ep = emb + r * 64 + e * 32 + quad * 8;
            f32x4 f0 = *(const f32x4*)ep;
            f32x4 f1 = *(const f32x4*)(ep + 4);
            bEmb[e] = pack8(f0, f1);
        }
        f32x4 einit[4], w2v[4];
        #pragma unroll
        for (int nn = 0; nn < 4; ++nn) {
            int fb = w * 64 + nn * 16 + quad * 4;
            einit[nn] = *(const f32x4*)(eb1 + r * 256 + fb);
            w2v[nn]  = *(const f32x4*)(ew2 + r * 256 + fb);
        }
        int mlo = lo >> 4, mhi = (hi - 1) >> 4;
        for (int m = mlo; m <= mhi; ++m) {    // block-uniform
            f32x4 acc[4];
            #pragma unroll
            for (int nn = 0; nn < 4; ++nn) acc[nn] = einit[nn];
            #pragma unroll
            for (int kt = 0; kt < 6; ++kt) {
                short8 cb;
                if (kt < 4)
                    cb = *(const short8*)((const char*)sX +
                            swzX(m * 16 + cc, kt * 64 + quad * 16));
                else
                    cb = bEmb[kt - 4];
                #pragma unroll
                for (int nn = 0; nn < 4; ++nn) {
                    short8 wa = *(const short8*)(pe +
                            ((size_t)((kt * 16 + (w * 4 + nn)) * 64 + lane)) * 8);
                    acc[nn] = MFMA16(wa, cb, acc[nn], 0, 0, 0);
                }
            }
            float s = 0.0f;
            #pragma unroll
            for (int nn = 0; nn < 4; ++nn)
                #pragma unroll
                for (int i = 0; i < 4; ++i)
                    s += fmaxf(acc[nn][i], 0.0f) * w2v[nn][i];
            s += __shfl_xor(s, 16);
            s += __shfl_xor(s, 32);
            int row = m * 16 + cc;                 // slot-space token row
            if (quad == 0 && row >= lo && row < hi) sRed[row][w] = s;
        }
    }
    __syncthreads();   // (4) partials visible

    // ---- final: sum 4 wave-partials + eb2[regime], scatter fp32 out ----
    if (t < 64) {                              // wave 0: lane t = slot t
        int rr = (t >= b1) + (t >= b2);
        f32x4 rv = *(const f32x4*)(&sRed[t][0]);
        out[ts + tos] = rv[0] + rv[1] + rv[2] + rv[3] + eb2[rr];
    }
}

extern "C" void kernel_launch(void* const* d_in, const int* in_sizes, int n_in,
                              void* d_out, int out_size, void* d_ws, size_t ws_size,
                              hipStream_t stream) {
    const float* x     = (const float*)d_in[0];
    const int*   rid   = (const int*)d_in[1];
    const float* fe_w1 = (const float*)d_in[2];
    const float* fe_b1 = (const float*)d_in[3];
    const float* fe_w2 = (const float*)d_in[4];
    const float* fe_b2 = (const float*)d_in[5];
    const float* emb   = (const float*)d_in[6];
    const float* ew1   = (const float*)d_in[7];
    const float* eb1   = (const float*)d_in[8];
    const float* ew2   = (const float*)d_in[9];
    const float* eb2   = (const float*)d_in[10];
    float* out = (float*)d_out;
    ushort* pw = (ushort*)d_ws;   // 425,984 bytes used

    hipLaunchKernelGGL(repack_weights, dim3(104), dim3(256), 0, stream,
                       fe_w1, fe_w2, ew1, pw);
    hipLaunchKernelGGL(fused_main, dim3(NTILES), dim3(256), 0, stream,
                       x, rid, pw, fe_b1, fe_b2, emb, eb1, ew2, eb2, out);
}

// Round 8
// 528.321 us; speedup vs baseline: 1.0655x; 1.0655x over previous
//
#include <hip/hip_runtime.h>

// RegimeAwareStudent: B=524288 tokens, ALL tensors fp32 (per reference), rid int32.
//   h  = relu(x @ fe_w1 + fe_b1)           [B,128]->[B,256]
//   f  = relu(h @ fe_w2 + fe_b2)           [B,256]->[B,128]
//   c  = concat(f, emb[rid])               [B,192]
//   eh = relu(c @ ew1[rid] + eb1[rid])     [B,192]->[B,256]
//   o  = eh @ ew2[rid] + eb2[rid]          [B,256]->[B,1]
// bf16 MFMA path (RNE at staging), fp32 accumulate, fp32 out.
// R8: R6/R7's transposed path abandoned (structural 137MB scratch writes,
// identical under two variants). Base = R5 (242us, clean counters). R5 was
// L2-BOUND: ~750KB/block of weight-fragment reads = ~25TB/s vs 34.5 L2 peak.
// Fixes:
//   * GLOBAL counting sort by regime (3 tiny kernels, 2.6MB ws): fused
//     blocks get 64 same-regime tokens -> stage-3 m-passes ragged~6.5 -> 4
//     (MFMA 156->96/block); boundary blocks (<=2) still handled by the
//     local ballot sort, which is kept.
//   * kt-outer stage 3 (all m-tiles per kt, acc[NT][4]): B-frags loaded
//     ONCE per block (24KB/wave) instead of once per m-pass -> stage-3 L2
//     traffic /4. Total ~224KB/block -> ~10TB/s, L2 unbound.
//   * ws fallback: if ws_size < 2.6MB, perm=nullptr == exact R5 behavior.

typedef short short8 __attribute__((ext_vector_type(8)));
typedef float f32x4  __attribute__((ext_vector_type(4)));

#define MFMA16 __builtin_amdgcn_mfma_f32_16x16x32_bf16

constexpr int B_TOK  = 524288;
constexpr int TM     = 64;                 // tokens per tile
constexpr int NTILES = B_TOK / TM;         // 8192, exact

// packed-weight layout in d_ws (ushort element offsets)
constexpr size_t PW1_OFF   = 0;            // fe_w1: 4kt*16nt*64lane*8 = 32768 el
constexpr size_t PW2_OFF   = 32768;        // fe_w2: 8kt*8nt*64*8      = 32768 el
constexpr size_t PE1_OFF   = 65536;        // ew1:   3 * 6kt*16nt*64*8 = 147456 el
constexpr size_t PE1_PER_R = 49152;
// weights end at byte 425,984. Then:
constexpr size_t PERM_BYTE = 425984;                 // uint perm[524288] = 2MB
constexpr size_t HIST_BYTE = PERM_BYTE + 2097152;    // uint hist[8192*3]
constexpr size_t WS_NEED   = HIST_BYTE + 98304;      // 2,621,440 B

static __device__ __forceinline__ ushort f2bf(float f) {  // RNE (repack only)
    union { float f; unsigned int i; } x; x.f = f;
    unsigned int i = x.i;
    i += 0x7fffu + ((i >> 16) & 1u);
    return (ushort)(i >> 16);
}

// HW packed f32->bf16 (RNE): D[15:0]=bf16(lo), D[31:16]=bf16(hi)
static __device__ __forceinline__ unsigned pk_bf16(float lo, float hi) {
    unsigned r;
    asm("v_cvt_pk_bf16_f32 %0, %1, %2" : "=v"(r) : "v"(lo), "v"(hi));
    return r;
}

static __device__ __forceinline__ short8 pack8(f32x4 f0, f32x4 f1) {
    union { unsigned u[4]; short8 s; } r;
    r.u[0] = pk_bf16(f0[0], f0[1]);
    r.u[1] = pk_bf16(f0[2], f0[3]);
    r.u[2] = pk_bf16(f1[0], f1[1]);
    r.u[3] = pk_bf16(f1[2], f1[3]);
    return r.s;
}

// X/F tile [64][128] bf16, row stride 256B. XOR row&15 into byte bits 4-7.
static __device__ __forceinline__ int swzX(int row, int inb) {
    return row * 256 + (inb ^ ((row & 15) << 4));
}
// H tile [64][256] bf16, row stride 512B. XOR row&7 into byte bits 4-6.
static __device__ __forceinline__ int swzH(int row, int inb) {
    return row * 512 + (inb ^ ((row & 7) << 4));
}

// ---- weight repack: fp32 -> bf16 MFMA B-fragment layout -------------------
__global__ void repack_weights(const float* __restrict__ w1,
                               const float* __restrict__ w2,
                               const float* __restrict__ e1,
                               ushort* __restrict__ pw) {
    int t = blockIdx.x * 256 + threadIdx.x;       // 26624 threads total
    const float* src; int N, kt, nt; size_t dst;
    int lane = t & 63;
    if (t < 4096) {                                // fe_w1: K=128,N=256
        int frag = t >> 6; kt = frag >> 4; nt = frag & 15;
        src = w1; N = 256; dst = PW1_OFF + (size_t)t * 8;
    } else if (t < 8192) {                         // fe_w2: K=256,N=128
        int u = t - 4096; int frag = u >> 6; kt = frag >> 3; nt = frag & 7;
        src = w2; N = 128; dst = PW2_OFF + (size_t)u * 8;
    } else {                                       // ew1[r]: K=192,N=256
        int u = t - 8192; int reg = u / 6144; int v = u % 6144;
        int frag = v >> 6; kt = frag >> 4; nt = frag & 15;
        src = e1 + (size_t)reg * (192 * 256); N = 256;
        dst = PE1_OFF + (size_t)reg * PE1_PER_R + (size_t)v * 8;
    }
    int quad = lane >> 4, cc = lane & 15;
    int k0 = kt * 32 + quad * 8;
    int n  = nt * 16 + cc;
    short8 vv;
    #pragma unroll
    for (int j = 0; j < 8; ++j) vv[j] = (short)f2bf(src[(size_t)(k0 + j) * N + n]);
    *(short8*)(pw + dst) = vv;
}

// ---- sort kernel 1: per-tile regime histogram (1 wave = 1 tile) -----------
__global__ void count_tiles(const int* __restrict__ rid, uint* __restrict__ hist) {
    int gt   = blockIdx.x * 256 + threadIdx.x;
    int tile = gt >> 6, lane = gt & 63;            // 8192 tiles exactly
    int myr = rid[tile * 64 + lane];
    int c0 = __popcll(__ballot(myr == 0));
    int c1 = __popcll(__ballot(myr == 1));
    int c2 = __popcll(__ballot(myr == 2));
    if (lane == 0) {
        hist[tile * 3 + 0] = (uint)c0;
        hist[tile * 3 + 1] = (uint)c1;
        hist[tile * 3 + 2] = (uint)c2;
    }
}

// ---- sort kernel 2: exclusive scan over logical order (r-major, tile) -----
__global__ void scan_bases(uint* __restrict__ hist) {
    __shared__ uint part[1024];
    int t = threadIdx.x;
    uint vals[24];
    uint s = 0;
    int base = t * 24;
    #pragma unroll
    for (int j = 0; j < 24; ++j) {
        int pos = base + j;                   // 0..24575
        int r = pos >> 13, tile = pos & 8191; // logical = r*8192 + tile
        vals[j] = hist[tile * 3 + r];
        s += vals[j];
    }
    part[t] = s;
    __syncthreads();
    for (int off = 1; off < 1024; off <<= 1) {   // inclusive Hillis-Steele
        uint v = (t >= off) ? part[t - off] : 0u;
        __syncthreads();
        part[t] += v;
        __syncthreads();
    }
    uint excl = (t == 0) ? 0u : part[t - 1];
    #pragma unroll
    for (int j = 0; j < 24; ++j) {
        int pos = base + j;
        int r = pos >> 13, tile = pos & 8191;
        uint v = vals[j];
        hist[tile * 3 + r] = excl;            // exclusive base for (r,tile)
        excl += v;
    }
}

// ---- sort kernel 3: scatter token ids into regime-sorted perm -------------
__global__ void scatter_perm(const int* __restrict__ rid,
                             const uint* __restrict__ hist,
                             uint* __restrict__ perm) {
    int gt   = blockIdx.x * 256 + threadIdx.x;
    int tile = gt >> 6, lane = gt & 63;
    int tok = tile * 64 + lane;
    int myr = rid[tok];
    unsigned long long below = (1ull << lane) - 1ull;
    int rank = 0;
    #pragma unroll
    for (int r = 0; r < 3; ++r) {
        unsigned long long mask = __ballot(myr == r);
        if (myr == r) rank = __popcll(mask & below);
    }
    perm[hist[tile * 3 + myr] + (uint)rank] = (uint)tok;
}

// stage-3 body, kt-outer over NT m-tiles: B-frags loaded once per kt.
#define STAGE3_TILES(NT)                                                        \
    {                                                                           \
        f32x4 acc[NT][4] = {};                                                  \
        _Pragma("unroll")                                                       \
        for (int kt = 0; kt < 6; ++kt) {                                        \
            short8 bfr[4];                                                      \
            _Pragma("unroll")                                                   \
            for (int nn = 0; nn < 4; ++nn)                                      \
                bfr[nn] = *(const short8*)(pe +                                 \
                        ((size_t)((kt * 16 + (w * 4 + nn)) * 64 + lane)) * 8);  \
            short8 a_[NT];                                                      \
            _Pragma("unroll")                                                   \
            for (int tt = 0; tt < NT; ++tt)                                     \
                a_[tt] = (kt < 4)                                               \
                    ? *(const short8*)((const char*)sX +                        \
                          swzX((mlo + tt) * 16 + c, kt * 64 + quad * 16))       \
                    : aEmb[kt - 4];                                             \
            _Pragma("unroll")                                                   \
            for (int tt = 0; tt < NT; ++tt)                                     \
                _Pragma("unroll")                                               \
                for (int nn = 0; nn < 4; ++nn)                                  \
                    acc[tt][nn] = MFMA16(a_[tt], bfr[nn], acc[tt][nn], 0, 0, 0);\
        }                                                                       \
        _Pragma("unroll")                                                       \
        for (int tt = 0; tt < NT; ++tt) {                                       \
            float s[4] = {0.f, 0.f, 0.f, 0.f};                                  \
            _Pragma("unroll")                                                   \
            for (int nn = 0; nn < 4; ++nn)                                      \
                _Pragma("unroll")                                               \
                for (int i = 0; i < 4; ++i)                                     \
                    s[i] += fmaxf(acc[tt][nn][i] + eb1v[nn], 0.0f) * w2v[nn];   \
            _Pragma("unroll")                                                   \
            for (int i = 0; i < 4; ++i) {                                       \
                s[i] += __shfl_xor(s[i], 1);                                    \
                s[i] += __shfl_xor(s[i], 2);                                    \
                s[i] += __shfl_xor(s[i], 4);                                    \
                s[i] += __shfl_xor(s[i], 8);                                    \
            }                                                                   \
            if (c == 0) {                                                       \
                _Pragma("unroll")                                               \
                for (int i = 0; i < 4; ++i) {                                   \
                    int row = (mlo + tt) * 16 + quad * 4 + i;                   \
                    if (row >= lo && row < hi) sRed[row][w] = s[i];             \
                }                                                               \
            }                                                                   \
        }                                                                       \
    }

// ---- fused main: 64 tokens per block (regime-sorted when perm!=null) ------
__global__ __launch_bounds__(256, 3) void fused_main(
    const float* __restrict__ x,
    const int*   __restrict__ rid,
    const uint*  __restrict__ perm,   // nullptr -> identity (R5 behavior)
    const ushort* __restrict__ pw,
    const float* __restrict__ fe_b1,
    const float* __restrict__ fe_b2,
    const float* __restrict__ emb,
    const float* __restrict__ eb1,
    const float* __restrict__ ew2,
    const float* __restrict__ eb2,
    float*       __restrict__ out) {
    __shared__ ushort sX[64 * 128];    // 16 KB: X tile, then F tile (slot rows)
    __shared__ ushort sH[64 * 256];    // 32 KB: H tile
    __shared__ float  sRed[64][4];     // 1 KB: per-wave partials

    const int t    = threadIdx.x;
    const int w    = t >> 6;
    const int lane = t & 63;
    const int quad = lane >> 4;
    const int c    = lane & 15;
    const int ts   = blockIdx.x * TM;

    // ---- stage X into LDS (local row = position in this block's list) ----
    #pragma unroll
    for (int it = 0; it < 4; ++it) {
        int chunk = it * 256 + t;
        int row = chunk >> 4, seg = chunk & 15;   // 8 floats per chunk
        int g = perm ? (int)perm[ts + row] : (ts + row);
        const float* xr = x + (size_t)g * 128 + seg * 8;
        f32x4 f0 = *(const f32x4*)xr;
        f32x4 f1 = *(const f32x4*)(xr + 4);
        *(short8*)((char*)sX + swzX(row, seg * 16)) = pack8(f0, f1);
    }

    // ---- per-wave (redundant, uniform) local sort of the 64 rows ----
    // After the global sort this is the identity for all but boundary blocks.
    int slot, b1, b2, tos;
    {
        int g = perm ? (int)perm[ts + lane] : (ts + lane);
        int myr = rid[g];
        unsigned long long below = (1ull << lane) - 1ull;
        int base = 0, bb1 = 0, bb2 = 0;
        slot = 0;
        #pragma unroll
        for (int r = 0; r < 3; ++r) {
            unsigned long long mask = __ballot(myr == r);
            if (myr == r) slot = base + __popcll(mask & below);
            base += __popcll(mask);
            if (r == 0) bb1 = base;
            if (r == 1) bb2 = base;
        }
        b1 = __builtin_amdgcn_readfirstlane(bb1);
        b2 = __builtin_amdgcn_readfirstlane(bb2);
        tos = __builtin_amdgcn_ds_permute(slot << 2, lane);  // slot s -> row
    }
    __syncthreads();   // (1) X visible

    // ---- stage 1: H = relu(X @ W1 + b1); wave cols [w*64, w*64+64) ----
    {
        f32x4 acc[4][4] = {};
        #pragma unroll
        for (int kt = 0; kt < 4; ++kt) {
            short8 a[4], b[4];
            #pragma unroll
            for (int m = 0; m < 4; ++m)
                a[m] = *(const short8*)((const char*)sX +
                        swzX(m * 16 + c, kt * 64 + quad * 16));
            #pragma unroll
            for (int nn = 0; nn < 4; ++nn)
                b[nn] = *(const short8*)(pw + PW1_OFF +
                        ((size_t)((kt * 16 + (w * 4 + nn)) * 64 + lane)) * 8);
            #pragma unroll
            for (int m = 0; m < 4; ++m)
                #pragma unroll
                for (int nn = 0; nn < 4; ++nn)
                    acc[m][nn] = MFMA16(a[m], b[nn], acc[m][nn], 0, 0, 0);
        }
        #pragma unroll
        for (int nn = 0; nn < 4; ++nn) {
            float bb = fe_b1[w * 64 + nn * 16 + c];
            #pragma unroll
            for (int m = 0; m < 4; ++m) {
                int col = w * 64 + nn * 16 + c;
                int r0  = m * 16 + quad * 4;
                float v0 = fmaxf(acc[m][nn][0] + bb, 0.0f);
                float v1 = fmaxf(acc[m][nn][1] + bb, 0.0f);
                float v2 = fmaxf(acc[m][nn][2] + bb, 0.0f);
                float v3 = fmaxf(acc[m][nn][3] + bb, 0.0f);
                unsigned p01 = pk_bf16(v0, v1);
                unsigned p23 = pk_bf16(v2, v3);
                *(ushort*)((char*)sH + swzH(r0 + 0, col * 2)) = (ushort)p01;
                *(ushort*)((char*)sH + swzH(r0 + 1, col * 2)) = (ushort)(p01 >> 16);
                *(ushort*)((char*)sH + swzH(r0 + 2, col * 2)) = (ushort)p23;
                *(ushort*)((char*)sH + swzH(r0 + 3, col * 2)) = (ushort)(p23 >> 16);
            }
        }
    }
    __syncthreads();   // (2) H visible; X region dead

    // ---- stage 2: F = relu(H @ W2 + b2); wave cols [w*32, w*32+32) ----
    {
        f32x4 acc[4][2] = {};
        #pragma unroll
        for (int kt = 0; kt < 8; ++kt) {
            short8 a[4], b[2];
            #pragma unroll
            for (int m = 0; m < 4; ++m)
                a[m] = *(const short8*)((const char*)sH +
                        swzH(m * 16 + c, kt * 64 + quad * 16));
            #pragma unroll
            for (int nn = 0; nn < 2; ++nn)
                b[nn] = *(const short8*)(pw + PW2_OFF +
                        ((size_t)((kt * 8 + (w * 2 + nn)) * 64 + lane)) * 8);
            #pragma unroll
            for (int m = 0; m < 4; ++m)
                #pragma unroll
                for (int nn = 0; nn < 2; ++nn)
                    acc[m][nn] = MFMA16(a[m], b[nn], acc[m][nn], 0, 0, 0);
        }
        float b2v[2];
        #pragma unroll
        for (int nn = 0; nn < 2; ++nn) b2v[nn] = fe_b2[w * 32 + nn * 16 + c];
        #pragma unroll
        for (int m = 0; m < 4; ++m) {
            int sr[4];
            #pragma unroll
            for (int i = 0; i < 4; ++i)
                sr[i] = __builtin_amdgcn_ds_bpermute((m * 16 + quad * 4 + i) << 2, slot);
            #pragma unroll
            for (int nn = 0; nn < 2; ++nn) {
                int col = w * 32 + nn * 16 + c;
                float v0 = fmaxf(acc[m][nn][0] + b2v[nn], 0.0f);
                float v1 = fmaxf(acc[m][nn][1] + b2v[nn], 0.0f);
                float v2 = fmaxf(acc[m][nn][2] + b2v[nn], 0.0f);
                float v3 = fmaxf(acc[m][nn][3] + b2v[nn], 0.0f);
                unsigned p01 = pk_bf16(v0, v1);
                unsigned p23 = pk_bf16(v2, v3);
                *(ushort*)((char*)sX + swzX(sr[0], col * 2)) = (ushort)p01;
                *(ushort*)((char*)sX + swzX(sr[1], col * 2)) = (ushort)(p01 >> 16);
                *(ushort*)((char*)sX + swzX(sr[2], col * 2)) = (ushort)p23;
                *(ushort*)((char*)sX + swzX(sr[3], col * 2)) = (ushort)(p23 >> 16);
            }
        }
    }
    __syncthreads();   // (3) F visible (slot space); H dead

    // ---- stage 3: per regime, kt-outer over its m-tile span ----
    for (int r = 0; r < 3; ++r) {
        int lo = (r == 0) ? 0  : (r == 1 ? b1 : b2);
        int hi = (r == 0) ? b1 : (r == 1 ? b2 : 64);
        if (lo >= hi) continue;               // block-uniform
        const ushort* pe = pw + PE1_OFF + (size_t)r * PE1_PER_R;
        short8 aEmb[2];
        #pragma unroll
        for (int e = 0; e < 2; ++e) {
            const float* ep = emb + r * 64 + e * 32 + quad * 8;
            f32x4 f0 = *(const f32x4*)ep;
            f32x4 f1 = *(const f32x4*)(ep + 4);
            aEmb[e] = pack8(f0, f1);
        }
        float eb1v[4], w2v[4];
        #pragma unroll
        for (int nn = 0; nn < 4; ++nn) {
            int col = w * 64 + nn * 16 + c;
            eb1v[nn] = eb1[r * 256 + col];
            w2v[nn]  = ew2[r * 256 + col];
        }
        int mlo = lo >> 4, mhi = (hi - 1) >> 4;
        switch (mhi - mlo) {
            case 0:  STAGE3_TILES(1); break;
            case 1:  STAGE3_TILES(2); break;
            case 2:  STAGE3_TILES(3); break;
            default: STAGE3_TILES(4); break;
        }
    }
    __syncthreads();   // (4) partials visible

    // ---- final: sum 4 wave-partials + eb2[regime], scatter fp32 out ----
    if (t < 64) {                              // wave 0: lane t = slot t
        int rr = (t >= b1) + (t >= b2);
        int g = perm ? (int)perm[ts + tos] : (ts + tos);
        f32x4 rv = *(const f32x4*)(&sRed[t][0]);
        out[g] = rv[0] + rv[1] + rv[2] + rv[3] + eb2[rr];
    }
}

extern "C" void kernel_launch(void* const* d_in, const int* in_sizes, int n_in,
                              void* d_out, int out_size, void* d_ws, size_t ws_size,
                              hipStream_t stream) {
    const float* x     = (const float*)d_in[0];
    const int*   rid   = (const int*)d_in[1];
    const float* fe_w1 = (const float*)d_in[2];
    const float* fe_b1 = (const float*)d_in[3];
    const float* fe_w2 = (const float*)d_in[4];
    const float* fe_b2 = (const float*)d_in[5];
    const float* emb   = (const float*)d_in[6];
    const float* ew1   = (const float*)d_in[7];
    const float* eb1   = (const float*)d_in[8];
    const float* ew2   = (const float*)d_in[9];
    const float* eb2   = (const float*)d_in[10];
    float* out = (float*)d_out;
    ushort* pw = (ushort*)d_ws;

    hipLaunchKernelGGL(repack_weights, dim3(104), dim3(256), 0, stream,
                       fe_w1, fe_w2, ew1, pw);

    const uint* permArg = nullptr;
    if (ws_size >= WS_NEED) {
        uint* perm = (uint*)((char*)d_ws + PERM_BYTE);
        uint* hist = (uint*)((char*)d_ws + HIST_BYTE);
        hipLaunchKernelGGL(count_tiles,  dim3(2048), dim3(256), 0, stream, rid, hist);
        hipLaunchKernelGGL(scan_bases,   dim3(1),    dim3(1024), 0, stream, hist);
        hipLaunchKernelGGL(scatter_perm, dim3(2048), dim3(256), 0, stream, rid, hist, perm);
        permArg = perm;
    }

    hipLaunchKernelGGL(fused_main, dim3(NTILES), dim3(256), 0, stream,
                       x, rid, permArg, pw, fe_b1, fe_b2, emb, eb1, ew2, eb2, out);
}